// Round 1
// baseline (23.139 us; speedup 1.0000x reference)
//
#include <hip/hip_runtime.h>

// Grid geometry (compile-time constants from the reference)
#define NXC   2048
#define PMLC  40
#define W     2128              // NXC + 2*PMLC
#define WV    532               // W / 4 float4's per row

__device__ __forceinline__ float clampedV(const float* __restrict__ vr, int j) {
    int vj = min(max(j - PMLC, 0), NXC - 1);
    return vr[vj];
}

__global__ __launch_bounds__(256) void wave_step(
    const float* __restrict__ p1,
    const float* __restrict__ p2,
    const float* __restrict__ varray,
    float* __restrict__ pout,
    float* __restrict__ col)
{
    const int v = blockIdx.x * blockDim.x + threadIdx.x;
    if (v >= W * WV) return;
    const int i  = v / WV;                 // row
    const int j0 = (v - i * WV) * 4;       // first column of this float4

    float4 out;
    if (i < 8 || i >= W - 8 || j0 < 8 || j0 >= W - 8) {
        // border: reference zeros everything outside [8, W-8)
        out = make_float4(0.f, 0.f, 0.f, 0.f);
    } else {
        constexpr float inv_dx2 = 1.0f / (10.0f * 10.0f);
        constexpr float dt2     = 0.0005f * 0.0005f;

        const float4 c  = *reinterpret_cast<const float4*>(&p2[(size_t)i * W + j0]);
        const float4 up = *reinterpret_cast<const float4*>(&p2[(size_t)(i - 1) * W + j0]);
        const float4 dn = *reinterpret_cast<const float4*>(&p2[(size_t)(i + 1) * W + j0]);
        const float4 a1 = *reinterpret_cast<const float4*>(&p1[(size_t)i * W + j0]);
        const float lft = p2[(size_t)i * W + j0 - 1];
        const float rgt = p2[(size_t)i * W + j0 + 4];

        const int vi = min(max(i - PMLC, 0), NXC - 1);
        const float* vr = &varray[(size_t)vi * NXC];

        const float cc[6]  = {lft, c.x, c.y, c.z, c.w, rgt};
        const float upk[4] = {up.x, up.y, up.z, up.w};
        const float dnk[4] = {dn.x, dn.y, dn.z, dn.w};
        const float a1k[4] = {a1.x, a1.y, a1.z, a1.w};
        float outk[4];

        #pragma unroll
        for (int k = 0; k < 4; ++k) {
            const float va    = clampedV(vr, j0 + k);
            const float alpha = va * va * dt2;
            const float ctr   = cc[k + 1];
            // (dpdx + dpdy): both second differences share the -2*center term
            const float lap = (cc[k] + cc[k + 2] - 2.0f * ctr
                             + upk[k] + dnk[k] - 2.0f * ctr) * inv_dx2;
            outk[k] = 2.0f * ctr - a1k[k] + alpha * lap;
        }
        out = make_float4(outk[0], outk[1], outk[2], outk[3]);

        // res[:, 50] = p[PML + r, PML + 50] = p[40 + r, 90]; 90 = j0 88, lane 2
        if (j0 == 88 && i >= PMLC && i < PMLC + NXC) {
            col[i - PMLC] = outk[2];
        }
    }
    *reinterpret_cast<float4*>(&pout[(size_t)i * W + j0]) = out;
}

__global__ void add_source(float* __restrict__ pout,
                           float* __restrict__ col,
                           const float* __restrict__ sf,
                           const int* __restrict__ xs_p,
                           const int* __restrict__ ys_p,
                           const int* __restrict__ t_p)
{
    const int xs = xs_p[0] + PMLC;
    const int ys = ys_p[0] + PMLC;
    const float add = sf[t_p[0]] * (0.0005f * 0.0005f);
    pout[(size_t)xs * W + ys] += add;
    // keep the extracted column consistent if the source lands on j == 90
    if (ys == PMLC + 50 && xs >= PMLC && xs < PMLC + NXC) {
        col[xs - PMLC] += add;
    }
}

extern "C" void kernel_launch(void* const* d_in, const int* in_sizes, int n_in,
                              void* d_out, int out_size, void* d_ws, size_t ws_size,
                              hipStream_t stream) {
    const float* p1 = (const float*)d_in[0];
    const float* p2 = (const float*)d_in[1];
    const float* va = (const float*)d_in[2];
    const float* sf = (const float*)d_in[3];
    const int* xs   = (const int*)d_in[4];
    const int* ys   = (const int*)d_in[5];
    const int* t    = (const int*)d_in[6];

    float* pout = (float*)d_out;              // W*W elements
    float* col  = (float*)d_out + (size_t)W * W;  // 2048 elements

    const int total_vec = W * WV;             // 1,132,096 float4-threads
    const int blocks = (total_vec + 255) / 256;
    wave_step<<<blocks, 256, 0, stream>>>(p1, p2, va, pout, col);
    add_source<<<1, 1, 0, stream>>>(pout, col, sf, xs, ys, t);
}

// Round 2
// 15.983 us; speedup vs baseline: 1.4477x; 1.4477x over previous
//
#include <hip/hip_runtime.h>

// Grid geometry (compile-time constants from the reference)
#define NXC   2048
#define PMLC  40
#define W     2128                    // NXC + 2*PMLC
#define WV    532                     // float4's per row
#define NWORK (W * WV)                // 1,132,096 vec4-threads
#define NBLK  ((NWORK + 255) / 256)   // 4423 blocks

__global__ __launch_bounds__(256) void wave_step(
    const float* __restrict__ p1,
    const float* __restrict__ p2,
    const float* __restrict__ varray,
    const float* __restrict__ sf,
    const int* __restrict__ xs_p,
    const int* __restrict__ ys_p,
    const int* __restrict__ t_p,
    float* __restrict__ pout,
    float* __restrict__ col)
{
    // Bijective XCD-chunk swizzle (T1, m204): each XCD gets a contiguous
    // band of rows so the up/dn stencil rows hit that XCD's private L2.
    constexpr int q = NBLK / 8, r = NBLK % 8;
    const int xcd = blockIdx.x & 7, pos = blockIdx.x >> 3;
    const int swz = (xcd < r ? xcd * (q + 1) : r * (q + 1) + (xcd - r) * q) + pos;
    const int v = (swz << 8) + (int)threadIdx.x;
    if (v >= NWORK) return;

    const int i  = v / WV;                 // row
    const int j0 = (v - i * WV) << 2;      // first column of this float4
    const size_t base = (size_t)i * W + j0;

    if (i < 8 || i >= W - 8 || j0 < 8 || j0 >= W - 8) {
        // reference zeros everything outside [8, W-8)
        *reinterpret_cast<float4*>(&pout[base]) = make_float4(0.f, 0.f, 0.f, 0.f);
        return;
    }

    constexpr float inv_dx2 = 1.0f / (10.0f * 10.0f);
    constexpr float dt2     = 0.0005f * 0.0005f;

    const float4 c  = *reinterpret_cast<const float4*>(&p2[base]);
    const float4 up = *reinterpret_cast<const float4*>(&p2[base - W]);
    const float4 dn = *reinterpret_cast<const float4*>(&p2[base + W]);
    const float4 a1 = *reinterpret_cast<const float4*>(&p1[base]);
    const float lft = p2[base - 1];
    const float rgt = p2[base + 4];

    const int vi = min(max(i - PMLC, 0), NXC - 1);
    const float* __restrict__ vr = &varray[(size_t)vi * NXC];

    // velocity row, edge-padded; vectorized in the common fully-interior case
    float vav[4];
    const int vj0 = j0 - PMLC;
    if (vj0 >= 0 && vj0 <= NXC - 4) {
        const float4 vv = *reinterpret_cast<const float4*>(&vr[vj0]);
        vav[0] = vv.x; vav[1] = vv.y; vav[2] = vv.z; vav[3] = vv.w;
    } else {
        #pragma unroll
        for (int k = 0; k < 4; ++k)
            vav[k] = vr[min(max(vj0 + k, 0), NXC - 1)];
    }

    const float cc[6]  = {lft, c.x, c.y, c.z, c.w, rgt};
    const float upk[4] = {up.x, up.y, up.z, up.w};
    const float dnk[4] = {dn.x, dn.y, dn.z, dn.w};
    const float a1k[4] = {a1.x, a1.y, a1.z, a1.w};
    float outk[4];

    #pragma unroll
    for (int k = 0; k < 4; ++k) {
        const float alpha = vav[k] * vav[k] * dt2;
        const float ctr   = cc[k + 1];
        const float lap   = (cc[k] + cc[k + 2] + upk[k] + dnk[k] - 4.0f * ctr) * inv_dx2;
        outk[k] = 2.0f * ctr - a1k[k] + alpha * lap;
    }

    // Fused source injection. For valid x_s,y_s in [0,2048) the source cell
    // (x_s+40, y_s+40) is always interior, so the owning thread handles it.
    const int xs = xs_p[0] + PMLC;
    const int ys = ys_p[0] + PMLC;
    if (i == xs) {
        const int d = ys - j0;
        if ((unsigned)d < 4u) {
            outk[d] += sf[t_p[0]] * dt2;
        }
    }

    // res[:, 50] = p[PML + r, PML + 50] = p[40 + r, 90]; 90 = j0 88, lane 2
    if (j0 == 88 && (unsigned)(i - PMLC) < (unsigned)NXC) {
        col[i - PMLC] = outk[2];
    }

    *reinterpret_cast<float4*>(&pout[base]) =
        make_float4(outk[0], outk[1], outk[2], outk[3]);
}

extern "C" void kernel_launch(void* const* d_in, const int* in_sizes, int n_in,
                              void* d_out, int out_size, void* d_ws, size_t ws_size,
                              hipStream_t stream) {
    const float* p1 = (const float*)d_in[0];
    const float* p2 = (const float*)d_in[1];
    const float* va = (const float*)d_in[2];
    const float* sf = (const float*)d_in[3];
    const int* xs   = (const int*)d_in[4];
    const int* ys   = (const int*)d_in[5];
    const int* t    = (const int*)d_in[6];

    float* pout = (float*)d_out;                   // W*W elements
    float* col  = (float*)d_out + (size_t)W * W;   // 2048 elements

    wave_step<<<NBLK, 256, 0, stream>>>(p1, p2, va, sf, xs, ys, t, pout, col);
}